// Round 6
// baseline (162.927 us; speedup 1.0000x reference)
//
#include <hip/hip_runtime.h>

#define DIM 128
#define EPS 1e-5f
#define GPB 8              // graphs per block

typedef short           bf16x8 __attribute__((ext_vector_type(8)));
typedef unsigned short  u16x4  __attribute__((ext_vector_type(4)));
typedef unsigned short  u16x8  __attribute__((ext_vector_type(8)));
typedef float           f32x4  __attribute__((ext_vector_type(4)));

__device__ __forceinline__ unsigned short f2b(float f) {
    unsigned int u = __builtin_bit_cast(unsigned int, f);
    unsigned int r = (u + 0x7FFFu + ((u >> 16) & 1u)) >> 16;   // RNE
    return (unsigned short)r;
}
__device__ __forceinline__ bf16x8 ldw8(const float* __restrict__ p) {
    f32x4 a = *reinterpret_cast<const f32x4*>(p);
    f32x4 b = *reinterpret_cast<const f32x4*>(p + 4);
    bf16x8 r;
    #pragma unroll
    for (int j = 0; j < 4; ++j) {
        r[j]     = (short)f2b(a[j]);
        r[j + 4] = (short)f2b(b[j]);
    }
    return r;
}

// ---------------------------------------------------------------------------
// K0: segment boundaries. bounds[b] = first n with batch[n] >= b, b in [0,nb].
// Each boundary has exactly one writer (sorted batch).
// ---------------------------------------------------------------------------
__global__ __launch_bounds__(256) void k_bounds(
    const int* __restrict__ batch, int* __restrict__ bounds, int n_nodes, int nb)
{
    const int idx = blockIdx.x * blockDim.x + threadIdx.x;
    if (idx > n_nodes) return;
    const int cur  = (idx < n_nodes) ? batch[idx] : nb;
    const int prev = (idx > 0) ? batch[idx - 1] : -1;
    for (int b = prev + 1; b <= cur; ++b) bounds[b] = idx;
}

// ---------------------------------------------------------------------------
// K1 (fused): one block = 8 graphs. 32 lanes/graph (2 row-sublanes x 16
// feature slots), in-lane unroll-by-2 => 4 independent 16B loads in flight.
// Phase 1: register pool -> xtile (rows 8..15 zero-padded for the MFMA tile).
// Phase 2: wave 0 runs Linear->LN->ReLU->Linear (MFMA 16x16x32) -> vtile.
// Phase 3: all threads re-walk segments (L3-warm) and NT-store h_out.
// ---------------------------------------------------------------------------
__global__ __launch_bounds__(256) void k_fused(
    const float* __restrict__ h, const int* __restrict__ bounds,
    const float* __restrict__ vn,
    const float* __restrict__ W1, const float* __restrict__ b1,
    const float* __restrict__ lng, const float* __restrict__ lnb,
    const float* __restrict__ W2, const float* __restrict__ b2v,
    float* __restrict__ vn_out, float* __restrict__ h_out, int n_nodes)
{
    __shared__ int sb[GPB + 1];
    __shared__ unsigned short xtile[16][136];   // bf16 MLP input tile (padded)
    __shared__ float vtile[16][132];            // f32 MLP output tile (padded)

    const int tid = threadIdx.x;
    const int G0  = blockIdx.x * GPB;

    if (tid < GPB + 1) sb[tid] = bounds[G0 + tid];

    // zero the pad rows 8..15 of xtile (cols 0..127)
    {
        const int zr = 8 + (tid >> 5);
        const int zc = (tid & 31) * 4;
        *reinterpret_cast<u16x4*>(&xtile[zr][zc]) = (u16x4){0, 0, 0, 0};
    }
    __syncthreads();

    const int gi   = tid >> 5;        // graph within block (0..7)
    const int l32  = tid & 31;
    const int rsub = l32 >> 4;        // row sublane (0/1)
    const int j    = l32 & 15;        // 8-feature slot
    const int s = sb[gi], e = sb[gi + 1];

    // ---- phase 1: pooled sum with 4 independent accumulators ----
    const f32x4 z4 = (f32x4){0.f, 0.f, 0.f, 0.f};
    f32x4 p0 = z4, p1 = z4, q0 = z4, q1 = z4;
    int n = s + rsub;
    for (; n + 2 < e; n += 4) {       // rows n and n+2 this iteration
        const float* r0 = h + (size_t)n * DIM + j * 8;
        const float* r1 = r0 + 2 * DIM;
        f32x4 x0 = *reinterpret_cast<const f32x4*>(r0);
        f32x4 x1 = *reinterpret_cast<const f32x4*>(r0 + 4);
        f32x4 y0 = *reinterpret_cast<const f32x4*>(r1);
        f32x4 y1 = *reinterpret_cast<const f32x4*>(r1 + 4);
        p0 += x0; p1 += x1; q0 += y0; q1 += y1;
    }
    if (n < e) {
        const float* r0 = h + (size_t)n * DIM + j * 8;
        p0 += *reinterpret_cast<const f32x4*>(r0);
        p1 += *reinterpret_cast<const f32x4*>(r0 + 4);
    }
    p0 += q0; p1 += q1;
    #pragma unroll
    for (int c = 0; c < 4; ++c) {     // reduce across the 2 row-sublanes
        p0[c] += __shfl_xor(p0[c], 16);
        p1[c] += __shfl_xor(p1[c], 16);
    }

    if (rsub == 0) {
        const int cnt = e - s;
        const float inv = 1.0f / (float)(cnt > 1 ? cnt : 1);
        const float* vp = vn + (size_t)(G0 + gi) * DIM + j * 8;
        f32x4 v0 = *reinterpret_cast<const f32x4*>(vp);
        f32x4 v1 = *reinterpret_cast<const f32x4*>(vp + 4);
        u16x8 xv;
        #pragma unroll
        for (int q = 0; q < 4; ++q) {
            xv[q]     = f2b(fmaf(p0[q], inv, v0[q]));
            xv[q + 4] = f2b(fmaf(p1[q], inv, v1[q]));
        }
        *reinterpret_cast<u16x8*>(&xtile[gi][j * 8]) = xv;
    }
    __syncthreads();

    // ---- phase 2: wave 0 runs the 2-layer MFMA MLP on the 16-row tile ----
    // A/B share the same (kgrp,kk,i)->k mapping -> k-permutation safe.
    // C/D (m89-verified): col n = lane&15, row m = (lane>>4)*4 + reg.
    if (tid < 64) {
        const int row16 = tid & 15;
        const int kgrp  = tid >> 4;

        bf16x8 afrag[4];
        #pragma unroll
        for (int kk = 0; kk < 4; ++kk)
            afrag[kk] = *reinterpret_cast<const bf16x8*>(&xtile[row16][kgrp * 8 + kk * 32]);

        f32x4 acc[8];
        #pragma unroll
        for (int t = 0; t < 8; ++t) acc[t] = (f32x4){0.f, 0.f, 0.f, 0.f};
        #pragma unroll
        for (int t = 0; t < 8; ++t) {
            const float* wp = W1 + (size_t)(t * 16 + row16) * DIM + kgrp * 8;
            #pragma unroll
            for (int kk = 0; kk < 4; ++kk) {
                bf16x8 bfrag = ldw8(wp + kk * 32);
                acc[t] = __builtin_amdgcn_mfma_f32_16x16x32_bf16(afrag[kk], bfrag, acc[t], 0, 0, 0);
            }
        }

        float b1f[8], gf[8], bf_[8], b2f8[8];
        #pragma unroll
        for (int t = 0; t < 8; ++t) {
            const int f = t * 16 + row16;
            b1f[t]  = b1[f];
            gf[t]   = lng[f];
            bf_[t]  = lnb[f];
            b2f8[t] = b2v[f];
        }
        #pragma unroll
        for (int t = 0; t < 8; ++t)
            #pragma unroll
            for (int r = 0; r < 4; ++r) acc[t][r] += b1f[t];

        // LayerNorm + ReLU -> z (bf16) back into xtile
        #pragma unroll
        for (int r = 0; r < 4; ++r) {
            float sm = 0.f, ss = 0.f;
            #pragma unroll
            for (int t = 0; t < 8; ++t) { sm += acc[t][r]; ss += acc[t][r] * acc[t][r]; }
            #pragma unroll
            for (int m = 1; m <= 8; m <<= 1) {
                sm += __shfl_xor(sm, m);
                ss += __shfl_xor(ss, m);
            }
            const float mu  = sm * (1.0f / 128.0f);
            const float var = ss * (1.0f / 128.0f) - mu * mu;
            const float rs  = rsqrtf(var + EPS);
            const int   gm  = kgrp * 4 + r;
            #pragma unroll
            for (int t = 0; t < 8; ++t) {
                float z = (acc[t][r] - mu) * rs * gf[t] + bf_[t];
                z = fmaxf(z, 0.f);
                xtile[gm][t * 16 + row16] = f2b(z);
            }
        }
        // wave-internal LDS ordering: reads below see this wave's writes

        bf16x8 afrag2[4];
        #pragma unroll
        for (int kk = 0; kk < 4; ++kk)
            afrag2[kk] = *reinterpret_cast<const bf16x8*>(&xtile[row16][kgrp * 8 + kk * 32]);

        f32x4 acc2[8];
        #pragma unroll
        for (int t = 0; t < 8; ++t) acc2[t] = (f32x4){0.f, 0.f, 0.f, 0.f};
        #pragma unroll
        for (int t = 0; t < 8; ++t) {
            const float* wp = W2 + (size_t)(t * 16 + row16) * DIM + kgrp * 8;
            #pragma unroll
            for (int kk = 0; kk < 4; ++kk) {
                bf16x8 bfrag = ldw8(wp + kk * 32);
                acc2[t] = __builtin_amdgcn_mfma_f32_16x16x32_bf16(afrag2[kk], bfrag, acc2[t], 0, 0, 0);
            }
        }

        #pragma unroll
        for (int r = 0; r < 4; ++r) {
            const int gm = kgrp * 4 + r;
            #pragma unroll
            for (int t = 0; t < 8; ++t)
                vtile[gm][t * 16 + row16] = acc2[t][r] + b2f8[t];
        }
    }
    __syncthreads();

    // ---- coalesced vn_out store (8 rows x 128 f32, one f32x4/thread) ----
    {
        float* dst = vn_out + (size_t)(G0 + gi) * DIM + l32 * 4;
        *reinterpret_cast<f32x4*>(dst) =
            *reinterpret_cast<const f32x4*>(&vtile[gi][l32 * 4]);
    }

    // ---- phase 3: h_out = h + vn_tile[gi], segment rows L3-warm ----
    f32x4 w0 = *reinterpret_cast<const f32x4*>(&vtile[gi][j * 8]);
    f32x4 w1 = *reinterpret_cast<const f32x4*>(&vtile[gi][j * 8 + 4]);
    n = s + rsub;
    for (; n + 2 < e; n += 4) {
        const float* r0 = h + (size_t)n * DIM + j * 8;
        const float* r1 = r0 + 2 * DIM;
        f32x4 x0 = *reinterpret_cast<const f32x4*>(r0);
        f32x4 x1 = *reinterpret_cast<const f32x4*>(r0 + 4);
        f32x4 y0 = *reinterpret_cast<const f32x4*>(r1);
        f32x4 y1 = *reinterpret_cast<const f32x4*>(r1 + 4);
        float* o0 = h_out + (size_t)n * DIM + j * 8;
        float* o1 = o0 + 2 * DIM;
        __builtin_nontemporal_store(x0 + w0, reinterpret_cast<f32x4*>(o0));
        __builtin_nontemporal_store(x1 + w1, reinterpret_cast<f32x4*>(o0 + 4));
        __builtin_nontemporal_store(y0 + w0, reinterpret_cast<f32x4*>(o1));
        __builtin_nontemporal_store(y1 + w1, reinterpret_cast<f32x4*>(o1 + 4));
    }
    if (n < e) {
        const float* r0 = h + (size_t)n * DIM + j * 8;
        f32x4 x0 = *reinterpret_cast<const f32x4*>(r0);
        f32x4 x1 = *reinterpret_cast<const f32x4*>(r0 + 4);
        float* o0 = h_out + (size_t)n * DIM + j * 8;
        __builtin_nontemporal_store(x0 + w0, reinterpret_cast<f32x4*>(o0));
        __builtin_nontemporal_store(x1 + w1, reinterpret_cast<f32x4*>(o0 + 4));
    }
}

// ---------------------------------------------------------------------------
extern "C" void kernel_launch(void* const* d_in, const int* in_sizes, int n_in,
                              void* d_out, int out_size, void* d_ws, size_t ws_size,
                              hipStream_t stream)
{
    const float* h    = (const float*)d_in[0];
    const int*   bat  = (const int*)d_in[1];
    const float* vn   = (const float*)d_in[2];
    const float* W1   = (const float*)d_in[3];
    const float* b1   = (const float*)d_in[4];
    const float* lng  = (const float*)d_in[5];
    const float* lnb  = (const float*)d_in[6];
    const float* W2   = (const float*)d_in[7];
    const float* b2v  = (const float*)d_in[8];

    const int n_nodes = in_sizes[0] / DIM;   // 500000
    const int nb      = in_sizes[2] / DIM;   // 8192

    float* out    = (float*)d_out;           // f32 output buffer
    float* h_out  = out;
    float* vn_out = out + (size_t)n_nodes * DIM;
    int*   bounds = (int*)d_ws;              // (nb+1) ints

    k_bounds<<<(n_nodes + 256) / 256, 256, 0, stream>>>(bat, bounds, n_nodes, nb);
    k_fused<<<nb / GPB, 256, 0, stream>>>(h, bounds, vn, W1, b1, lng, lnb,
                                          W2, b2v, vn_out, h_out, n_nodes);
}

// Round 7
// 160.052 us; speedup vs baseline: 1.0180x; 1.0180x over previous
//
#include <hip/hip_runtime.h>

#define DIM 128
#define EPS 1e-5f

typedef short           bf16x8 __attribute__((ext_vector_type(8)));
typedef unsigned short  u16x4  __attribute__((ext_vector_type(4)));
typedef float           f32x4  __attribute__((ext_vector_type(4)));

__device__ __forceinline__ unsigned short f2b(float f) {
    unsigned int u = __builtin_bit_cast(unsigned int, f);
    unsigned int r = (u + 0x7FFFu + ((u >> 16) & 1u)) >> 16;   // RNE
    return (unsigned short)r;
}
__device__ __forceinline__ bf16x8 ldw8(const float* __restrict__ p) {
    f32x4 a = *reinterpret_cast<const f32x4*>(p);
    f32x4 b = *reinterpret_cast<const f32x4*>(p + 4);
    bf16x8 r;
    #pragma unroll
    for (int j = 0; j < 4; ++j) {
        r[j]     = (short)f2b(a[j]);
        r[j + 4] = (short)f2b(b[j]);
    }
    return r;
}

// ---------------------------------------------------------------------------
// K0: segment boundaries. bounds[b] = first n with batch[n] >= b, b in [0,nb].
// ---------------------------------------------------------------------------
__global__ __launch_bounds__(256) void k_bounds(
    const int* __restrict__ batch, int* __restrict__ bounds, int n_nodes, int nb)
{
    const int idx = blockIdx.x * blockDim.x + threadIdx.x;
    if (idx > n_nodes) return;
    const int cur  = (idx < n_nodes) ? batch[idx] : nb;
    const int prev = (idx > 0) ? batch[idx - 1] : -1;
    for (int b = prev + 1; b <= cur; ++b) bounds[b] = idx;
}

// ---------------------------------------------------------------------------
// K1: pool. One WAVE per graph, zero barriers, pure read stream.
// 32 lanes/row (f32x4 each), 2 row-sublanes, unrolled so 4 independent
// 16B loads are in flight per lane. 8192 waves -> full 32 waves/CU.
// Writes x = pooled/cnt + vn_h as bf16 to x_ws (primes L3 with h).
// ---------------------------------------------------------------------------
__global__ __launch_bounds__(256) void k_pool(
    const float* __restrict__ h, const int* __restrict__ bounds,
    const float* __restrict__ vn, unsigned short* __restrict__ x_ws, int nb)
{
    const int wid  = (blockIdx.x * blockDim.x + threadIdx.x) >> 6;  // graph
    const int lane = threadIdx.x & 63;
    if (wid >= nb) return;
    const int rsub = lane >> 5;        // row sublane (0/1)
    const int l32  = lane & 31;        // f32x4 slot within row
    const int s = bounds[wid], e = bounds[wid + 1];

    const f32x4 z4 = (f32x4){0.f, 0.f, 0.f, 0.f};
    f32x4 a0 = z4, a1 = z4, a2 = z4, a3 = z4;
    int n = s;
    for (; n + 7 < e; n += 8) {        // rows n..n+7, 4 loads/lane in flight
        const float* p = h + (size_t)(n + rsub) * DIM + l32 * 4;
        f32x4 x0 = *reinterpret_cast<const f32x4*>(p);
        f32x4 x1 = *reinterpret_cast<const f32x4*>(p + 2 * DIM);
        f32x4 x2 = *reinterpret_cast<const f32x4*>(p + 4 * DIM);
        f32x4 x3 = *reinterpret_cast<const f32x4*>(p + 6 * DIM);
        a0 += x0; a1 += x1; a2 += x2; a3 += x3;
    }
    for (; n + rsub < e; n += 2)
        a0 += *reinterpret_cast<const f32x4*>(h + (size_t)(n + rsub) * DIM + l32 * 4);
    a0 += a1; a2 += a3; a0 += a2;
    #pragma unroll
    for (int c = 0; c < 4; ++c) a0[c] += __shfl_xor(a0[c], 32);

    if (rsub == 0) {
        const int cnt = e - s;
        const float inv = 1.0f / (float)(cnt > 1 ? cnt : 1);
        f32x4 vv = *reinterpret_cast<const f32x4*>(vn + (size_t)wid * DIM + l32 * 4);
        u16x4 ov;
        #pragma unroll
        for (int q = 0; q < 4; ++q) ov[q] = f2b(fmaf(a0[q], inv, vv[q]));
        *reinterpret_cast<u16x4*>(x_ws + (size_t)wid * DIM + l32 * 4) = ov;
    }
}

// ---------------------------------------------------------------------------
// K2: vn MLP (proven round-3 version). MFMA 16x16x32 bf16, one wave per
// 16 graphs, 4 waves/block. Direct f32 store of vn_out.
// ---------------------------------------------------------------------------
__global__ __launch_bounds__(256) void k_mlp(
    const unsigned short* __restrict__ x_ws,
    const float* __restrict__ W1, const float* __restrict__ b1,
    const float* __restrict__ lng, const float* __restrict__ lnb,
    const float* __restrict__ W2, const float* __restrict__ b2v,
    float* __restrict__ vn_out)
{
    __shared__ unsigned short zt[4][16][136];

    const int wave  = threadIdx.x >> 6;
    const int lane  = threadIdx.x & 63;
    const int gtile = blockIdx.x * 4 + wave;
    const int row16 = lane & 15;
    const int kgrp  = lane >> 4;

    bf16x8 afrag[4];
    {
        const unsigned short* xp =
            x_ws + (size_t)(gtile * 16 + row16) * DIM + kgrp * 8;
        #pragma unroll
        for (int kk = 0; kk < 4; ++kk)
            afrag[kk] = *reinterpret_cast<const bf16x8*>(xp + kk * 32);
    }
    f32x4 acc[8];
    #pragma unroll
    for (int t = 0; t < 8; ++t) acc[t] = (f32x4){0.f, 0.f, 0.f, 0.f};
    #pragma unroll
    for (int t = 0; t < 8; ++t) {
        const float* wp = W1 + (size_t)(t * 16 + row16) * DIM + kgrp * 8;
        #pragma unroll
        for (int kk = 0; kk < 4; ++kk) {
            bf16x8 bfrag = ldw8(wp + kk * 32);
            acc[t] = __builtin_amdgcn_mfma_f32_16x16x32_bf16(afrag[kk], bfrag, acc[t], 0, 0, 0);
        }
    }

    float b1f[8], gf[8], bf_[8], b2f8[8];
    #pragma unroll
    for (int t = 0; t < 8; ++t) {
        const int f = t * 16 + row16;
        b1f[t]  = b1[f];
        gf[t]   = lng[f];
        bf_[t]  = lnb[f];
        b2f8[t] = b2v[f];
    }
    #pragma unroll
    for (int t = 0; t < 8; ++t)
        #pragma unroll
        for (int r = 0; r < 4; ++r) acc[t][r] += b1f[t];

    #pragma unroll
    for (int r = 0; r < 4; ++r) {
        float sm = 0.f, ss = 0.f;
        #pragma unroll
        for (int t = 0; t < 8; ++t) { sm += acc[t][r]; ss += acc[t][r] * acc[t][r]; }
        #pragma unroll
        for (int m = 1; m <= 8; m <<= 1) {
            sm += __shfl_xor(sm, m);
            ss += __shfl_xor(ss, m);
        }
        const float mu  = sm * (1.0f / 128.0f);
        const float var = ss * (1.0f / 128.0f) - mu * mu;
        const float rs  = rsqrtf(var + EPS);
        const int   gm  = kgrp * 4 + r;
        #pragma unroll
        for (int t = 0; t < 8; ++t) {
            float z = (acc[t][r] - mu) * rs * gf[t] + bf_[t];
            z = fmaxf(z, 0.f);
            zt[wave][gm][t * 16 + row16] = f2b(z);
        }
    }
    __syncthreads();

    bf16x8 afrag2[4];
    #pragma unroll
    for (int kk = 0; kk < 4; ++kk)
        afrag2[kk] = *reinterpret_cast<const bf16x8*>(&zt[wave][row16][kk * 32 + kgrp * 8]);

    f32x4 acc2[8];
    #pragma unroll
    for (int t = 0; t < 8; ++t) acc2[t] = (f32x4){0.f, 0.f, 0.f, 0.f};
    #pragma unroll
    for (int t = 0; t < 8; ++t) {
        const float* wp = W2 + (size_t)(t * 16 + row16) * DIM + kgrp * 8;
        #pragma unroll
        for (int kk = 0; kk < 4; ++kk) {
            bf16x8 bfrag = ldw8(wp + kk * 32);
            acc2[t] = __builtin_amdgcn_mfma_f32_16x16x32_bf16(afrag2[kk], bfrag, acc2[t], 0, 0, 0);
        }
    }

    #pragma unroll
    for (int r = 0; r < 4; ++r) {
        float* op = vn_out + (size_t)(gtile * 16 + kgrp * 4 + r) * DIM + row16;
        #pragma unroll
        for (int t = 0; t < 8; ++t)
            op[t * 16] = acc2[t][r] + b2f8[t];
    }
}

// ---------------------------------------------------------------------------
// K3: h_out = h + vn_out[batch]. Pure grid-stride streamer, no barriers.
// h is L3-warm from K1; NT stores keep the write stream out of L3.
// ---------------------------------------------------------------------------
__global__ __launch_bounds__(256) void k_add(
    const float* __restrict__ h, const int* __restrict__ batch,
    const float* __restrict__ vn_out, float* __restrict__ h_out,
    int n_nodes)
{
    const long total = (long)n_nodes * 16;     // 16 8-float units per row
    for (long u = (long)blockIdx.x * blockDim.x + threadIdx.x; u < total;
         u += (long)gridDim.x * blockDim.x) {
        const int n = (int)(u >> 4);
        const int c = ((int)u & 15) * 8;
        const float* hp = h + (size_t)n * DIM + c;
        f32x4 h0 = *reinterpret_cast<const f32x4*>(hp);
        f32x4 h1 = *reinterpret_cast<const f32x4*>(hp + 4);
        const int b = batch[n];
        const float* vp = vn_out + (size_t)b * DIM + c;
        f32x4 v0 = *reinterpret_cast<const f32x4*>(vp);
        f32x4 v1 = *reinterpret_cast<const f32x4*>(vp + 4);
        float* op = h_out + (size_t)n * DIM + c;
        __builtin_nontemporal_store(h0 + v0, reinterpret_cast<f32x4*>(op));
        __builtin_nontemporal_store(h1 + v1, reinterpret_cast<f32x4*>(op + 4));
    }
}

// ---------------------------------------------------------------------------
extern "C" void kernel_launch(void* const* d_in, const int* in_sizes, int n_in,
                              void* d_out, int out_size, void* d_ws, size_t ws_size,
                              hipStream_t stream)
{
    const float* h    = (const float*)d_in[0];
    const int*   bat  = (const int*)d_in[1];
    const float* vn   = (const float*)d_in[2];
    const float* W1   = (const float*)d_in[3];
    const float* b1   = (const float*)d_in[4];
    const float* lng  = (const float*)d_in[5];
    const float* lnb  = (const float*)d_in[6];
    const float* W2   = (const float*)d_in[7];
    const float* b2v  = (const float*)d_in[8];

    const int n_nodes = in_sizes[0] / DIM;   // 500000
    const int nb      = in_sizes[2] / DIM;   // 8192

    float* out    = (float*)d_out;           // f32 output buffer
    float* h_out  = out;
    float* vn_out = out + (size_t)n_nodes * DIM;
    int*   bounds = (int*)d_ws;              // (nb+1) ints
    unsigned short* x_ws =
        (unsigned short*)((char*)d_ws + ((size_t)(nb + 1) * 4 + 255 & ~255ull));

    k_bounds<<<(n_nodes + 256) / 256, 256, 0, stream>>>(bat, bounds, n_nodes, nb);
    k_pool<<<nb / 4, 256, 0, stream>>>(h, bounds, vn, x_ws, nb);
    k_mlp<<<nb / 64, 256, 0, stream>>>(x_ws, W1, b1, lng, lnb, W2, b2v, vn_out);
    k_add<<<2048, 256, 0, stream>>>(h, bat, vn_out, h_out, n_nodes);
}